// Round 31
// baseline (417.345 us; speedup 1.0000x reference)
//
#include <hip/hip_runtime.h>
#include <hip/hip_bf16.h>
#include <math.h>

// ---------------------------------------------------------------------------
// SPNet: GCN(2x) -> masked edge attention -> encoder -> 3 MLP heads
// N=100000, E=1600000, F=H=128.
// Round 31: eliminate the k_prep dispatch. Weight transposes fold into
//   k_fillB (640 extra blocks, uniform branch, independent work); the x->xp
//   cvt folds into k_sortC (each block converts its own 512 nodes using the
//   in-LDS cnt[] it already computed; bit-identical dv=rsqrtf(cnt+1)).
//   Dispatch chain 8 -> 7; cvt streaming overlaps sortC scatter latency.
//   LEDGER: (1) LDS b128 row strides must be 16B multiples.
//           (2) intra-block pipelining redundant at >=3 blocks/CU.
//           (3) tail plateau invariant to occupancy/blocking/staging.
//           (4) never trade gather parallelism for fusion.
//           (5) launch/latency-dominated pipeline: eliminating passes and
//               dispatches beats intra-kernel optimization.
//           (6) x->xp bf16 compaction halves gather-phase BW; keep it.
// ---------------------------------------------------------------------------

#define BCAP 12288

using bf16x8 = __attribute__((ext_vector_type(8))) short;
using s16x8  = __attribute__((ext_vector_type(8))) short;
using f32x4  = __attribute__((ext_vector_type(4))) float;

static __device__ __forceinline__ float lrelu02(float x) { return x > 0.f ? x : 0.2f * x; }

static __device__ __forceinline__ unsigned short f2bf(float f) {
    unsigned u = __float_as_uint(f);
    unsigned r = u + 0x7FFF + ((u >> 16) & 1);   // round-to-nearest-even
    return (unsigned short)(r >> 16);
}
static __device__ __forceinline__ float bf2f(unsigned short h) {
    return __uint_as_float(((unsigned)h) << 16);
}
static __device__ __forceinline__ float bflo(unsigned u) { return __uint_as_float(u << 16); }
static __device__ __forceinline__ float bfhi(unsigned u) { return __uint_as_float(u & 0xFFFF0000u); }

// ---------------- CSR build + weight prep (fused) ----------------

// blocks [0,eblk): partition edges into PADDED dst-buckets; payload =
// src | dlo<<20 | tbit<<29. pcur[b] ends as bucket count; pcnt_m[b] = masked.
// blocks [eblk, eblk+640): weight transposes (independent work).
__global__ __launch_bounds__(256) void k_fillB(const int* __restrict__ src,
                                               const int* __restrict__ dst,
                                               const int* __restrict__ t,
                                               int* __restrict__ pcur,
                                               int* __restrict__ pcnt_m,
                                               int* __restrict__ ebuf,
                                               int e, int shift, int eblk,
                                               const float* __restrict__ Wo,
                                               const float* __restrict__ Wti,
                                               const float* __restrict__ Wenc,
                                               const float* __restrict__ p1W1,
                                               const float* __restrict__ p1W2,
                                               const float* __restrict__ p0W1,
                                               const float* __restrict__ p0W2,
                                               const float* __restrict__ dW1,
                                               const float* __restrict__ dW2,
                                               unsigned short* __restrict__ Wcat_t,
                                               unsigned short* __restrict__ Wenc_t,
                                               unsigned short* __restrict__ o1,
                                               unsigned short* __restrict__ o2,
                                               unsigned short* __restrict__ o3,
                                               unsigned short* __restrict__ o4,
                                               unsigned short* __restrict__ o5,
                                               unsigned short* __restrict__ o6) {
    if (blockIdx.x >= eblk) {
        // ---- weight transpose branch ----
        int idx = (blockIdx.x - eblk) * 256 + threadIdx.x;
        if (idx < 32768) {
            int j = idx >> 7, k = idx & 127;
            float v = (j < 128) ? Wo[(k << 7) + j] : Wti[(k << 7) + j - 128];
            Wcat_t[idx] = f2bf(v);
        } else if (idx < 65536) {
            int i = idx - 32768;
            Wenc_t[(size_t)(i & 127) * 256 + (i >> 7)] = f2bf(Wenc[i]);
        } else {
            int i2 = idx - 65536;
            int h = i2 >> 14;
            int i = i2 & 16383;
            const float* W; unsigned short* O;
            switch (h) {
                case 0: W = p1W1; O = o1; break;
                case 1: W = p1W2; O = o2; break;
                case 2: W = p0W1; O = o3; break;
                case 3: W = p0W2; O = o4; break;
                case 4: W = dW1;  O = o5; break;
                default: W = dW2; O = o6; break;
            }
            O[(i & 127) * 128 + (i >> 7)] = f2bf(W[i]);
        }
        return;
    }
    __shared__ int h[256], hm[256];
    const int EPT = 16;
    int blk_base = blockIdx.x * 256 * EPT;
    h[threadIdx.x] = 0; hm[threadIdx.x] = 0;
    __syncthreads();
    int pk[EPT], bk[EPT];
#pragma unroll
    for (int j = 0; j < EPT; ++j) {
        int i = blk_base + threadIdx.x + j * 256;
        if (i < e) {
            int s = src[i], d = dst[i];
            int b = d >> shift;
            bk[j] = b;
            int tb = (t[s] > 0) ? 1 : 0;
            pk[j] = s | ((d - (b << shift)) << 20) | (tb << 29);
            atomicAdd(&h[b], 1);
            if (tb) atomicAdd(&hm[b], 1);
        } else bk[j] = -1;
    }
    __syncthreads();
    int cnt = h[threadIdx.x];
    int base = 0;
    if (cnt > 0) base = atomicAdd(&pcur[threadIdx.x], cnt);
    int cm = hm[threadIdx.x];
    if (cm > 0) atomicAdd(&pcnt_m[threadIdx.x], cm);
    __syncthreads();
    h[threadIdx.x] = base;   // running within-bucket cursor for this block
    __syncthreads();
#pragma unroll
    for (int j = 0; j < EPT; ++j) {
        if (bk[j] >= 0) {
            int pos = atomicAdd(&h[bk[j]], 1);
            if (pos < BCAP)
                ebuf[(size_t)bk[j] * BCAP + pos] = pk[j];
        }
    }
}

// pass C: one block per bucket. In-block 256-bucket prefix scan, LDS counting
// sort of the PADDED bucket slice, then x->xp cvt for this block's 512 nodes.
__global__ __launch_bounds__(256) void k_sortC(const int* __restrict__ ebuf,
                                               const int* __restrict__ pcur,
                                               const int* __restrict__ pcnt_m,
                                               int* __restrict__ indptr,
                                               int* __restrict__ indptr_m,
                                               float* __restrict__ dinv,
                                               int* __restrict__ out_all,
                                               int* __restrict__ out_m,
                                               const float* __restrict__ x,
                                               unsigned short* __restrict__ xp,
                                               int n, int shift, int NB) {
    __shared__ int sA[256], sB[256];
    __shared__ int cnt[512], cnt_m[512];
    __shared__ int cur[512], cur_m[512];
    __shared__ int tmp[256];
    int tid = threadIdx.x;
    int b = blockIdx.x;

    // ---- dual inclusive scan of bucket histograms ----
    sA[tid] = pcur[tid];
    sB[tid] = pcnt_m[tid];
    __syncthreads();
    for (int off = 1; off < 256; off <<= 1) {
        int uA = (tid >= off) ? sA[tid - off] : 0;
        int uB = (tid >= off) ? sB[tid - off] : 0;
        __syncthreads();
        sA[tid] += uA; sB[tid] += uB;
        __syncthreads();
    }
    int lo      = (b > 0) ? sA[b - 1] : 0;
    int lom     = (b > 0) ? sB[b - 1] : 0;
    int cnt_tot = sA[b] - lo;

    const int* eb = ebuf + (size_t)b * BCAP;
    int dbase = b << shift;
    for (int j = tid; j < 512; j += 256) { cnt[j] = 0; cnt_m[j] = 0; }
    __syncthreads();
    for (int i = tid; i < cnt_tot; i += 256) {
        int pk = eb[i];
        int dlo = (pk >> 20) & 511;
        atomicAdd(&cnt[dlo], 1);
        if (pk >> 29) atomicAdd(&cnt_m[dlo], 1);
    }
    __syncthreads();
    int c0 = cnt[2 * tid], c1 = cnt[2 * tid + 1];
    int ps = c0 + c1;
    tmp[tid] = ps;
    __syncthreads();
    for (int off = 1; off < 256; off <<= 1) {
        int u = (tid >= off) ? tmp[tid - off] : 0;
        __syncthreads();
        tmp[tid] += u;
        __syncthreads();
    }
    int pre = tmp[tid] - ps;
    cur[2 * tid] = pre;
    cur[2 * tid + 1] = pre + c0;
    __syncthreads();
    int m0 = cnt_m[2 * tid], m1 = cnt_m[2 * tid + 1];
    int psm = m0 + m1;
    tmp[tid] = psm;
    __syncthreads();
    for (int off = 1; off < 256; off <<= 1) {
        int u = (tid >= off) ? tmp[tid - off] : 0;
        __syncthreads();
        tmp[tid] += u;
        __syncthreads();
    }
    int prem = tmp[tid] - psm;
    cur_m[2 * tid] = prem;
    cur_m[2 * tid + 1] = prem + m0;
    __syncthreads();
    int nd = n - dbase; if (nd > 512) nd = 512;
    for (int j = tid; j < nd; j += 256) {
        indptr[dbase + j] = lo + cur[j];
        indptr_m[dbase + j] = lom + cur_m[j];
        dinv[dbase + j] = rsqrtf((float)cnt[j] + 1.0f);   // self-loop adds 1
    }
    if (b == 0 && tid == 0) {
        indptr[n] = sA[255];
        indptr_m[n] = sB[255];
    }
    __syncthreads();
    for (int i = tid; i < cnt_tot; i += 256) {
        int pk = eb[i];
        int s = pk & 0xFFFFF;
        int dlo = (pk >> 20) & 511;
        int pos = lo + atomicAdd(&cur[dlo], 1);
        out_all[pos] = s;
        if (pk >> 29) {
            int pm = lom + atomicAdd(&cur_m[dlo], 1);
            out_m[pm] = s;
        }
    }
    // ---- x->xp cvt for this block's nodes (cnt[] intact; dv bit-identical) --
    for (int i = tid; i < nd * 32; i += 256) {
        int row = i >> 5;
        float dv = rsqrtf((float)cnt[row] + 1.0f);
        float4 v = ((const float4*)x)[(size_t)(dbase + row) * 32 + (i & 31)];
        ushort4 o;
        o.x = f2bf(v.x * dv); o.y = f2bf(v.y * dv);
        o.z = f2bf(v.z * dv); o.w = f2bf(v.w * dv);
        ((ushort4*)xp)[(size_t)(dbase + row) * 32 + (i & 31)] = o;
    }
}

// ---------------- graph: aggregate x_pre ----------------
__global__ __launch_bounds__(256) void k_aggx(const unsigned short* __restrict__ xp,
                                              const int* __restrict__ indptr,
                                              const int* __restrict__ srcs,
                                              const float* __restrict__ dinv,
                                              unsigned short* __restrict__ aggx, int n) {
    int wv = threadIdx.x >> 6, lane = threadIdx.x & 63;
    int v = blockIdx.x * 4 + wv;
    if (v >= n) return;
    const unsigned* xp2 = (const unsigned*)xp;
    int beg = indptr[v], end = indptr[v + 1];
    unsigned sv = xp2[(size_t)v * 64 + lane];
    float a0 = bflo(sv), a1 = bfhi(sv);
    int i = beg;
    for (; i + 8 <= end; i += 8) {
        int s0 = srcs[i], s1 = srcs[i + 1], s2 = srcs[i + 2], s3 = srcs[i + 3];
        int s4 = srcs[i + 4], s5 = srcs[i + 5], s6 = srcs[i + 6], s7 = srcs[i + 7];
        unsigned u0 = xp2[(size_t)s0 * 64 + lane];
        unsigned u1 = xp2[(size_t)s1 * 64 + lane];
        unsigned u2 = xp2[(size_t)s2 * 64 + lane];
        unsigned u3 = xp2[(size_t)s3 * 64 + lane];
        unsigned u4 = xp2[(size_t)s4 * 64 + lane];
        unsigned u5 = xp2[(size_t)s5 * 64 + lane];
        unsigned u6 = xp2[(size_t)s6 * 64 + lane];
        unsigned u7 = xp2[(size_t)s7 * 64 + lane];
        a0 += bflo(u0) + bflo(u1) + bflo(u2) + bflo(u3)
            + bflo(u4) + bflo(u5) + bflo(u6) + bflo(u7);
        a1 += bfhi(u0) + bfhi(u1) + bfhi(u2) + bfhi(u3)
            + bfhi(u4) + bfhi(u5) + bfhi(u6) + bfhi(u7);
    }
    for (; i + 4 <= end; i += 4) {
        int s0 = srcs[i], s1 = srcs[i + 1], s2 = srcs[i + 2], s3 = srcs[i + 3];
        unsigned u0 = xp2[(size_t)s0 * 64 + lane];
        unsigned u1 = xp2[(size_t)s1 * 64 + lane];
        unsigned u2 = xp2[(size_t)s2 * 64 + lane];
        unsigned u3 = xp2[(size_t)s3 * 64 + lane];
        a0 += bflo(u0) + bflo(u1) + bflo(u2) + bflo(u3);
        a1 += bfhi(u0) + bfhi(u1) + bfhi(u2) + bfhi(u3);
    }
    for (; i < end; ++i) {
        unsigned u = xp2[(size_t)srcs[i] * 64 + lane];
        a0 += bflo(u); a1 += bfhi(u);
    }
    float dv = dinv[v];
    a0 *= dv; a1 *= dv;
    unsigned o = (unsigned)f2bf(a0) | ((unsigned)f2bf(a1) << 16);
    ((unsigned*)aggx)[(size_t)v * 64 + lane] = o;
}

// ---------------- GCN gemm: [r_o|r_t] = relu(aggx @ Wcat + [b_o|b_t]), e fused
__global__ __launch_bounds__(256) void k_gcn(const unsigned short* __restrict__ aggx,
                                             const unsigned short* __restrict__ Wcat,
                                             const float* __restrict__ b_o,
                                             const float* __restrict__ b_t,
                                             const float* __restrict__ a_w,
                                             const float* __restrict__ a_b,
                                             unsigned short* __restrict__ cat2,
                                             unsigned short* __restrict__ rt,
                                             float* __restrict__ e, int M) {
    __shared__ short ct[64][264];   // 64 rows x 256 cols bf16 (+8 pad, 528B rows)
    int wave = threadIdx.x >> 6, lane = threadIdx.x & 63;
    int row_base = blockIdx.x * 64 + wave * 16;
    int rA = row_base + (lane & 15);
    if (rA >= M) rA = M - 1;
    int koff = (lane >> 4) << 3;
    int colL = lane & 15;

    bf16x8 a[4];
#pragma unroll
    for (int ks = 0; ks < 4; ++ks)
        a[ks] = *(const bf16x8*)((const short*)aggx + (size_t)rA * 128 + (ks << 5) + koff);

    f32x4 acc[16];
#pragma unroll
    for (int cf = 0; cf < 16; ++cf) acc[cf] = (f32x4){0.f, 0.f, 0.f, 0.f};
#pragma unroll
    for (int ks = 0; ks < 4; ++ks)
#pragma unroll
        for (int cf = 0; cf < 16; ++cf) {
            bf16x8 b = *(const bf16x8*)((const short*)Wcat + (size_t)((cf << 4) + colL) * 128 + (ks << 5) + koff);
            acc[cf] = __builtin_amdgcn_mfma_f32_16x16x32_bf16(a[ks], b, acc[cf], 0, 0, 0);
        }

    float ep0 = 0.f, ep1 = 0.f, ep2 = 0.f, ep3 = 0.f;
    int rl0 = wave * 16 + ((lane >> 4) << 2);
#pragma unroll
    for (int cf = 0; cf < 16; ++cf) {
        int col = (cf << 4) + colL;
        float bv = (col < 128) ? b_o[col] : b_t[col - 128];
        float aw = a_w[col];
#pragma unroll
        for (int j = 0; j < 4; ++j) {
            float v = fmaxf(acc[cf][j] + bv, 0.f);
            if (j == 0) ep0 += v * aw;
            else if (j == 1) ep1 += v * aw;
            else if (j == 2) ep2 += v * aw;
            else ep3 += v * aw;
            ct[rl0 + j][col] = (short)f2bf(v);
        }
    }
#pragma unroll
    for (int mk = 1; mk < 16; mk <<= 1) {
        ep0 += __shfl_xor(ep0, mk); ep1 += __shfl_xor(ep1, mk);
        ep2 += __shfl_xor(ep2, mk); ep3 += __shfl_xor(ep3, mk);
    }
    if (colL == 0) {
        float ab = a_b[0];
        int r0 = row_base + ((lane >> 4) << 2);
        if (r0 + 0 < M) e[r0 + 0] = ep0 + ab;
        if (r0 + 1 < M) e[r0 + 1] = ep1 + ab;
        if (r0 + 2 < M) e[r0 + 2] = ep2 + ab;
        if (r0 + 3 < M) e[r0 + 3] = ep3 + ab;
    }
    __syncthreads();
    int base64 = blockIdx.x * 64;
    short* cp = (short*)cat2 + (size_t)base64 * 256;
    for (int j = threadIdx.x; j < 1024; j += 256) {
        int row = j >> 4;
        if (base64 + row < M)
            *(s16x8*)(cp + (size_t)row * 256 + ((j & 15) << 3)) =
                *(const s16x8*)&ct[row][(j & 15) << 3];
    }
    short* rp = (short*)rt + (size_t)base64 * 128;
    for (int j = threadIdx.x; j < 1024; j += 256) {
        int row = j >> 4;
        if (base64 + row < M)
            *(s16x8*)(rp + (size_t)row * 128 + ((j & 15) << 3)) =
                *(const s16x8*)&ct[row][128 + ((j & 15) << 3)];
    }
}

// ---------------- masked attention (masked CSR only) ----------------
__global__ __launch_bounds__(256) void k_attn(const unsigned short* __restrict__ rt,
                                              const int* __restrict__ indptr_m,
                                              const int* __restrict__ srcs_m,
                                              const float* __restrict__ e,
                                              unsigned short* __restrict__ cat2, int n) {
    int wv = threadIdx.x >> 6, lane = threadIdx.x & 63;
    int v = blockIdx.x * 4 + wv;
    if (v >= n) return;
    float ev = e[v];
    int bm = indptr_m[v], em = indptr_m[v + 1];
    float m = -INFINITY;
    for (int i = bm + lane; i < em; i += 64)
        m = fmaxf(m, lrelu02(ev + e[srcs_m[i]]));
    for (int off = 32; off; off >>= 1) m = fmaxf(m, __shfl_xor(m, off));
    if (bm == em) m = 0.f;
    float h0 = 0.f, h1 = 0.f, wsum = 0.f;
    const unsigned* rt2 = (const unsigned*)rt;
    int i = bm;
    for (; i + 8 <= em; i += 8) {
        int s0 = srcs_m[i], s1 = srcs_m[i + 1], s2 = srcs_m[i + 2], s3 = srcs_m[i + 3];
        int s4 = srcs_m[i + 4], s5 = srcs_m[i + 5], s6 = srcs_m[i + 6], s7 = srcs_m[i + 7];
        float w0 = __expf(lrelu02(ev + e[s0]) - m);
        float w1 = __expf(lrelu02(ev + e[s1]) - m);
        float w2 = __expf(lrelu02(ev + e[s2]) - m);
        float w3 = __expf(lrelu02(ev + e[s3]) - m);
        float w4 = __expf(lrelu02(ev + e[s4]) - m);
        float w5 = __expf(lrelu02(ev + e[s5]) - m);
        float w6 = __expf(lrelu02(ev + e[s6]) - m);
        float w7 = __expf(lrelu02(ev + e[s7]) - m);
        unsigned u0 = rt2[(size_t)s0 * 64 + lane];
        unsigned u1 = rt2[(size_t)s1 * 64 + lane];
        unsigned u2 = rt2[(size_t)s2 * 64 + lane];
        unsigned u3 = rt2[(size_t)s3 * 64 + lane];
        unsigned u4 = rt2[(size_t)s4 * 64 + lane];
        unsigned u5 = rt2[(size_t)s5 * 64 + lane];
        unsigned u6 = rt2[(size_t)s6 * 64 + lane];
        unsigned u7 = rt2[(size_t)s7 * 64 + lane];
        wsum += w0 + w1 + w2 + w3 + w4 + w5 + w6 + w7;
        h0 += w0 * bflo(u0) + w1 * bflo(u1) + w2 * bflo(u2) + w3 * bflo(u3)
            + w4 * bflo(u4) + w5 * bflo(u5) + w6 * bflo(u6) + w7 * bflo(u7);
        h1 += w0 * bfhi(u0) + w1 * bfhi(u1) + w2 * bfhi(u2) + w3 * bfhi(u3)
            + w4 * bfhi(u4) + w5 * bfhi(u5) + w6 * bfhi(u6) + w7 * bfhi(u7);
    }
    for (; i < em; ++i) {
        int s = srcs_m[i];
        float w = __expf(lrelu02(ev + e[s]) - m);
        unsigned u = rt2[(size_t)s * 64 + lane];
        wsum += w;
        h0 += w * bflo(u);
        h1 += w * bfhi(u);
    }
    float inv = 1.f / (wsum + 1e-16f);
    unsigned o = (unsigned)f2bf(h0 * inv) | ((unsigned)f2bf(h1 * inv) << 16);
    ((unsigned*)(cat2 + (size_t)v * 256 + 128))[lane] = o;
}

// ---------------- fused tail: z_enc GEMM + 3 MLP heads + select/sigmoid ----
// 512 threads / 8 waves / 128 rows per block; wave owns 16 rows. Pool 69632 B
// (2 blocks/CU, 16 waves/CU): Wa [128][136] shorts (34816 B) overlaid by zt
// [64][132] fp32 (33792 B); hb [128][136] shorts (34816 B, wave-indexed).
// Phase-1 zt staging in 2 chunks (waves 0-3, then 4-7).
__global__ __launch_bounds__(512) void k_tail(
    const unsigned short* __restrict__ cat2, const unsigned short* __restrict__ rt_bf,
    const unsigned short* __restrict__ Wenc, const float* __restrict__ b_enc,
    const unsigned short* __restrict__ W11, const float* __restrict__ b11,
    const unsigned short* __restrict__ W12, const float* __restrict__ b12,
    const float* __restrict__ W13, const float* __restrict__ b13,
    const unsigned short* __restrict__ W01, const float* __restrict__ b01,
    const unsigned short* __restrict__ W02, const float* __restrict__ b02,
    const float* __restrict__ W03, const float* __restrict__ b03,
    const unsigned short* __restrict__ Wd1, const float* __restrict__ bd1,
    const unsigned short* __restrict__ Wd2, const float* __restrict__ bd2,
    const float* __restrict__ Wd3, const float* __restrict__ bd3,
    const int* __restrict__ t, float* __restrict__ zenc,
    float* __restrict__ out, int M) {
    __shared__ __align__(16) char pool[128 * 136 * 2 + 128 * 136 * 2];   // 69632 B
    short* Wa = (short*)pool;                       // 34816 B
    short* hb = (short*)(pool + 128 * 136 * 2);     // 34816 B
    float* zt = (float*)pool;                       // [64][132] fp32 = 33792 B

    int wave = threadIdx.x >> 6, lane = threadIdx.x & 63;
    int colL = lane & 15;
    int koff = (lane >> 4) << 3;
    int base128 = blockIdx.x * 128;
    int rA = base128 + wave * 16 + colL;
    if (rA >= M) rA = M - 1;

    // ra frags (discriminator input) — load early, hides under phase 1
    bf16x8 ra[4];
#pragma unroll
    for (int ks = 0; ks < 4; ++ks)
        ra[ks] = *(const bf16x8*)((const short*)rt_bf + (size_t)rA * 128 + (ks << 5) + koff);

    // ---- phase 1: z_enc (K=256, Ncols=128) for this wave's 16 rows ----
    f32x4 acc1[8];
    {
        const short* Ap = (const short*)cat2 + (size_t)rA * 256 + koff;
        const short* Bp = (const short*)Wenc + (size_t)colL * 256 + koff;
#pragma unroll
        for (int cf = 0; cf < 8; ++cf) acc1[cf] = (f32x4){0.f, 0.f, 0.f, 0.f};
#pragma unroll
        for (int ks = 0; ks < 8; ++ks) {
            bf16x8 a = *(const bf16x8*)(Ap + (ks << 5));
#pragma unroll
            for (int cf = 0; cf < 8; ++cf) {
                bf16x8 b = *(const bf16x8*)(Bp + (size_t)(cf << 4) * 256 + (ks << 5));
                acc1[cf] = __builtin_amdgcn_mfma_f32_16x16x32_bf16(a, b, acc1[cf], 0, 0, 0);
            }
        }
    }

    // ---- zt staging + zenc writeout + za extraction, in 2 wave-group chunks
    bf16x8 za[4];
#pragma unroll
    for (int chunk = 0; chunk < 2; ++chunk) {
        if ((wave >> 2) == chunk) {
            int rl0 = (wave & 3) * 16 + ((lane >> 4) << 2);
#pragma unroll
            for (int cf = 0; cf < 8; ++cf) {
                int col = (cf << 4) + colL;
                float bv = b_enc[col];
#pragma unroll
                for (int j = 0; j < 4; ++j)
                    zt[(rl0 + j) * 132 + col] = acc1[cf][j] + bv;
            }
        }
        __syncthreads();
        {   // cooperative linear fp32 writeout of this chunk's 64x128 region
            int gbase = base128 + chunk * 64;
            float* zp = zenc + (size_t)gbase * 128;
            for (int j = threadIdx.x; j < 2048; j += 512) {
                int row = j >> 5;
                if (gbase + row < M)
                    *(float4*)(zp + (size_t)j * 4) = *(const float4*)&zt[row * 132 + ((j & 31) << 2)];
            }
        }
        if ((wave >> 2) == chunk) {
            int rAl = (wave & 3) * 16 + colL;
#pragma unroll
            for (int ks = 0; ks < 4; ++ks) {
                float4 v0 = *(const float4*)&zt[rAl * 132 + (ks << 5) + koff];
                float4 v1 = *(const float4*)&zt[rAl * 132 + (ks << 5) + koff + 4];
                za[ks][0] = (short)f2bf(v0.x); za[ks][1] = (short)f2bf(v0.y);
                za[ks][2] = (short)f2bf(v0.z); za[ks][3] = (short)f2bf(v0.w);
                za[ks][4] = (short)f2bf(v1.x); za[ks][5] = (short)f2bf(v1.y);
                za[ks][6] = (short)f2bf(v1.z); za[ks][7] = (short)f2bf(v1.w);
            }
        }
        __syncthreads();   // zt reads done before next chunk / Wa staging
    }

    float sp1[4], sp0[4], sdd[4];

    auto stage = [&](const unsigned short* W) {
        for (int i = threadIdx.x; i < 2048; i += 512) {
            int r = i >> 4, c = (i & 15) << 3;
            bf16x8 v = *(const bf16x8*)((const short*)W + (r << 7) + c);
            *(bf16x8*)(Wa + r * 136 + c) = v;
        }
    };

    auto run_head = [&](const bf16x8* A0,
                        const unsigned short* W1, const float* b1,
                        const unsigned short* W2, const float* b2,
                        const float* W3, const float* b3, float* sout) {
        __syncthreads();   // Wa/hb reads of previous head done (1st call: zt done)
        stage(W1);
        __syncthreads();
        f32x4 acc[8];
#pragma unroll
        for (int cf = 0; cf < 8; ++cf) acc[cf] = (f32x4){0.f, 0.f, 0.f, 0.f};
#pragma unroll
        for (int ks = 0; ks < 4; ++ks)
#pragma unroll
            for (int cf = 0; cf < 8; ++cf) {
                bf16x8 b = *(const bf16x8*)(Wa + ((cf << 4) + colL) * 136 + (ks << 5) + koff);
                acc[cf] = __builtin_amdgcn_mfma_f32_16x16x32_bf16(A0[ks], b, acc[cf], 0, 0, 0);
            }
        short* hw = hb + wave * 2176;   // 16 rows x 136 shorts per wave
#pragma unroll
        for (int cf = 0; cf < 8; ++cf) {
            int col = (cf << 4) + colL;
            float bv = b1[col];
#pragma unroll
            for (int j = 0; j < 4; ++j)
                hw[(((lane >> 4) << 2) + j) * 136 + col] = (short)f2bf(lrelu02(acc[cf][j] + bv));
        }
        __syncthreads();   // all MFMA1 reads of Wa done; hb written
        stage(W2);
        __syncthreads();
        bf16x8 h1f[4];
#pragma unroll
        for (int ks = 0; ks < 4; ++ks)
            h1f[ks] = *(const bf16x8*)(hw + colL * 136 + (ks << 5) + koff);
#pragma unroll
        for (int cf = 0; cf < 8; ++cf) acc[cf] = (f32x4){0.f, 0.f, 0.f, 0.f};
#pragma unroll
        for (int ks = 0; ks < 4; ++ks)
#pragma unroll
            for (int cf = 0; cf < 8; ++cf) {
                bf16x8 b = *(const bf16x8*)(Wa + ((cf << 4) + colL) * 136 + (ks << 5) + koff);
                acc[cf] = __builtin_amdgcn_mfma_f32_16x16x32_bf16(h1f[ks], b, acc[cf], 0, 0, 0);
            }
        float s0 = 0.f, s1 = 0.f, s2 = 0.f, s3 = 0.f;
#pragma unroll
        for (int cf = 0; cf < 8; ++cf) {
            int col = (cf << 4) + colL;
            float w3 = W3[col], bv = b2[col];
            s0 += lrelu02(acc[cf][0] + bv) * w3;
            s1 += lrelu02(acc[cf][1] + bv) * w3;
            s2 += lrelu02(acc[cf][2] + bv) * w3;
            s3 += lrelu02(acc[cf][3] + bv) * w3;
        }
#pragma unroll
        for (int mk = 1; mk < 16; mk <<= 1) {
            s0 += __shfl_xor(s0, mk); s1 += __shfl_xor(s1, mk);
            s2 += __shfl_xor(s2, mk); s3 += __shfl_xor(s3, mk);
        }
        float bb = b3[0];
        sout[0] = s0 + bb; sout[1] = s1 + bb; sout[2] = s2 + bb; sout[3] = s3 + bb;
    };

    run_head(za, W11, b11, W12, b12, W13, b13, sp1);
    run_head(za, W01, b01, W02, b02, W03, b03, sp0);
    run_head(ra, Wd1, bd1, Wd2, bd2, Wd3, bd3, sdd);

    if (colL == 0) {
#pragma unroll
        for (int j = 0; j < 4; ++j) {
            int row = base128 + wave * 16 + ((lane >> 4) << 2) + j;
            if (row < M) {
                out[row] = 1.f / (1.f + __expf(-sdd[j]));           // pred_t
                out[M + row] = (t[row] > 0) ? sp1[j] : sp0[j];      // pred
            }
        }
    }
}

// ---------------- launcher ----------------

extern "C" void kernel_launch(void* const* d_in, const int* in_sizes, int n_in,
                              void* d_out, int out_size, void* d_ws, size_t ws_size,
                              hipStream_t stream) {
    const float* x     = (const float*)d_in[0];
    const int*   t     = (const int*)d_in[1];
    const int*   ei    = (const int*)d_in[3];
    const float* W_o   = (const float*)d_in[4];
    const float* b_o   = (const float*)d_in[5];
    const float* W_t   = (const float*)d_in[6];
    const float* b_t   = (const float*)d_in[7];
    const float* a_w   = (const float*)d_in[8];
    const float* a_b   = (const float*)d_in[9];
    const float* W_enc = (const float*)d_in[10];
    const float* b_enc = (const float*)d_in[11];
    const float* p1_W1 = (const float*)d_in[12]; const float* p1_b1 = (const float*)d_in[13];
    const float* p1_W2 = (const float*)d_in[14]; const float* p1_b2 = (const float*)d_in[15];
    const float* p1_W3 = (const float*)d_in[16]; const float* p1_b3 = (const float*)d_in[17];
    const float* p0_W1 = (const float*)d_in[18]; const float* p0_b1 = (const float*)d_in[19];
    const float* p0_W2 = (const float*)d_in[20]; const float* p0_b2 = (const float*)d_in[21];
    const float* p0_W3 = (const float*)d_in[22]; const float* p0_b3 = (const float*)d_in[23];
    const float* d_W1  = (const float*)d_in[24]; const float* d_b1  = (const float*)d_in[25];
    const float* d_W2  = (const float*)d_in[26]; const float* d_b2  = (const float*)d_in[27];
    const float* d_W3  = (const float*)d_in[28]; const float* d_b3  = (const float*)d_in[29];

    const int n = in_sizes[1];
    const int E = in_sizes[3] / 2;
    const int* src = ei;
    const int* dst = ei + E;

    float* out  = (float*)d_out;
    float* zenc = out + 2 * (size_t)n;   // output: pred_t[N], pred[N], z_enc[N,128]

    const int shift = 9;
    const int NB = (n + (1 << shift) - 1) >> shift;

    // ---- workspace layout ----
    char* base = (char*)d_ws;
    size_t o = 0;
    auto alloc = [&](size_t bytes) { char* p = base + o; o += (bytes + 255) & ~(size_t)255; return p; };
    unsigned short* xp_bf   = (unsigned short*)alloc((size_t)n * 128 * 2);
    unsigned short* aggx_bf = (unsigned short*)alloc((size_t)n * 128 * 2);
    unsigned short* cat2_bf = (unsigned short*)alloc((size_t)n * 256 * 2);
    unsigned short* rt_bf   = (unsigned short*)alloc((size_t)n * 128 * 2);
    float* dinv = (float*)alloc((size_t)n * 4);
    float* evec = (float*)alloc((size_t)n * 4);
    unsigned short* Wcat_t = (unsigned short*)alloc(256 * 128 * 2);
    unsigned short* Wenc_t = (unsigned short*)alloc(128 * 256 * 2);
    unsigned short* Wp1a_t = (unsigned short*)alloc(128 * 128 * 2);
    unsigned short* Wp1b_t = (unsigned short*)alloc(128 * 128 * 2);
    unsigned short* Wp0a_t = (unsigned short*)alloc(128 * 128 * 2);
    unsigned short* Wp0b_t = (unsigned short*)alloc(128 * 128 * 2);
    unsigned short* Wda_t  = (unsigned short*)alloc(128 * 128 * 2);
    unsigned short* Wdb_t  = (unsigned short*)alloc(128 * 128 * 2);
    int* indptr     = (int*)alloc(((size_t)n + 1) * 4);
    int* indptr_m   = (int*)alloc(((size_t)n + 1) * 4);
    int* pcur       = (int*)alloc(514 * 4);          // pcur[257] + pcnt_m[257]
    int* pcnt_m     = pcur + 257;
    int* src_sorted = (int*)alloc((size_t)E * 4);
    int* src_mask   = (int*)alloc((size_t)E * 4);
    int* ebuf       = (int*)alloc((size_t)256 * BCAP * 4);   // padded buckets

    const int mt  = (n + 63) / 64;
    const int mt2 = (n + 127) / 128;
    const int eblk = (E + 4095) / 4096;

    // ---- CSR build + weight prep (fused); scan+cvt folded into sortC ----
    hipMemsetAsync(pcur, 0, 514 * 4, stream);
    k_fillB<<<eblk + 640, 256, 0, stream>>>(src, dst, t, pcur, pcnt_m, ebuf, E, shift, eblk,
                                            W_o, W_t, W_enc, p1_W1, p1_W2, p0_W1, p0_W2,
                                            d_W1, d_W2, Wcat_t, Wenc_t,
                                            Wp1a_t, Wp1b_t, Wp0a_t, Wp0b_t, Wda_t, Wdb_t);
    k_sortC<<<NB, 256, 0, stream>>>(ebuf, pcur, pcnt_m, indptr, indptr_m, dinv,
                                    src_sorted, src_mask, x, xp_bf, n, shift, NB);

    // aggregate prescaled x over full CSR
    k_aggx<<<(n + 3) / 4, 256, 0, stream>>>(xp_bf, indptr, src_sorted, dinv, aggx_bf, n);

    // [r_o|r_t] = relu(aggx @ Wcat + bias); e fused
    k_gcn<<<mt, 256, 0, stream>>>(aggx_bf, Wcat_t, b_o, b_t, a_w, a_b,
                                  cat2_bf, rt_bf, evec, n);

    // attention -> h (masked CSR only)
    k_attn<<<(n + 3) / 4, 256, 0, stream>>>(rt_bf, indptr_m, src_mask, evec, cat2_bf, n);

    // fused: z_enc + 3 heads + select/sigmoid (512 threads, 128 rows/block)
    k_tail<<<mt2, 512, 0, stream>>>(cat2_bf, rt_bf, Wenc_t, b_enc,
                                    Wp1a_t, p1_b1, Wp1b_t, p1_b2, p1_W3, p1_b3,
                                    Wp0a_t, p0_b1, Wp0b_t, p0_b2, p0_W3, p0_b3,
                                    Wda_t, d_b1, Wdb_t, d_b2, d_W3, d_b3,
                                    t, zenc, out, n);
}

// Round 32
// 393.648 us; speedup vs baseline: 1.0602x; 1.0602x over previous
//
#include <hip/hip_runtime.h>
#include <hip/hip_bf16.h>
#include <math.h>

// ---------------------------------------------------------------------------
// SPNet: GCN(2x) -> masked edge attention -> encoder -> 3 MLP heads
// N=100000, E=1600000, F=H=128.
// Round 32: FINAL — revert r31 (cvt fold into 196-block sortC cut the 77MB
//   stream's TLP ~10x: +22us). This is r28's proven best (394.1us, repro
//   395.3 r30). Pipeline: memset -> fillB -> sortC(+scan) -> prep(wprep+cvt)
//   -> aggx -> gcn -> attn -> tail.
//   LEDGER: (1) LDS b128 row strides must be 16B multiples.
//           (2) intra-block pipelining redundant at >=3 blocks/CU.
//           (3) tail plateau invariant to occupancy/blocking/staging.
//           (4) never trade gather parallelism for fusion.
//           (5) launch/latency-dominated pipeline: eliminating passes and
//               dispatches beats intra-kernel optimization.
//           (6) x->xp bf16 compaction halves gather-phase BW; keep it.
//           (7) fold work only into kernels of comparable grid size.
// ---------------------------------------------------------------------------

#define BCAP 12288

using bf16x8 = __attribute__((ext_vector_type(8))) short;
using s16x8  = __attribute__((ext_vector_type(8))) short;
using f32x4  = __attribute__((ext_vector_type(4))) float;

static __device__ __forceinline__ float lrelu02(float x) { return x > 0.f ? x : 0.2f * x; }

static __device__ __forceinline__ unsigned short f2bf(float f) {
    unsigned u = __float_as_uint(f);
    unsigned r = u + 0x7FFF + ((u >> 16) & 1);   // round-to-nearest-even
    return (unsigned short)(r >> 16);
}
static __device__ __forceinline__ float bf2f(unsigned short h) {
    return __uint_as_float(((unsigned)h) << 16);
}
static __device__ __forceinline__ float bflo(unsigned u) { return __uint_as_float(u << 16); }
static __device__ __forceinline__ float bfhi(unsigned u) { return __uint_as_float(u & 0xFFFF0000u); }

// ---------------- CSR build ----------------

// single pass: partition edges into PADDED dst-buckets; payload =
// src | dlo<<20 | tbit<<29. pcur[b] ends as bucket count; pcnt_m[b] = masked.
__global__ __launch_bounds__(256) void k_fillB(const int* __restrict__ src,
                                               const int* __restrict__ dst,
                                               const int* __restrict__ t,
                                               int* __restrict__ pcur,
                                               int* __restrict__ pcnt_m,
                                               int* __restrict__ ebuf,
                                               int e, int shift) {
    __shared__ int h[256], hm[256];
    const int EPT = 16;
    int blk_base = blockIdx.x * 256 * EPT;
    h[threadIdx.x] = 0; hm[threadIdx.x] = 0;
    __syncthreads();
    int pk[EPT], bk[EPT];
#pragma unroll
    for (int j = 0; j < EPT; ++j) {
        int i = blk_base + threadIdx.x + j * 256;
        if (i < e) {
            int s = src[i], d = dst[i];
            int b = d >> shift;
            bk[j] = b;
            int tb = (t[s] > 0) ? 1 : 0;
            pk[j] = s | ((d - (b << shift)) << 20) | (tb << 29);
            atomicAdd(&h[b], 1);
            if (tb) atomicAdd(&hm[b], 1);
        } else bk[j] = -1;
    }
    __syncthreads();
    int cnt = h[threadIdx.x];
    int base = 0;
    if (cnt > 0) base = atomicAdd(&pcur[threadIdx.x], cnt);
    int cm = hm[threadIdx.x];
    if (cm > 0) atomicAdd(&pcnt_m[threadIdx.x], cm);
    __syncthreads();
    h[threadIdx.x] = base;   // running within-bucket cursor for this block
    __syncthreads();
#pragma unroll
    for (int j = 0; j < EPT; ++j) {
        if (bk[j] >= 0) {
            int pos = atomicAdd(&h[bk[j]], 1);
            if (pos < BCAP)
                ebuf[(size_t)bk[j] * BCAP + pos] = pk[j];
        }
    }
}

// pass C: one block per bucket. In-block 256-bucket prefix scan (replaces
// k_scan2), then LDS counting sort of the PADDED bucket slice.
__global__ __launch_bounds__(256) void k_sortC(const int* __restrict__ ebuf,
                                               const int* __restrict__ pcur,
                                               const int* __restrict__ pcnt_m,
                                               int* __restrict__ indptr,
                                               int* __restrict__ indptr_m,
                                               float* __restrict__ dinv,
                                               int* __restrict__ out_all,
                                               int* __restrict__ out_m,
                                               int n, int shift, int NB) {
    __shared__ int sA[256], sB[256];
    __shared__ int cnt[512], cnt_m[512];
    __shared__ int cur[512], cur_m[512];
    __shared__ int tmp[256];
    int tid = threadIdx.x;
    int b = blockIdx.x;

    // ---- dual inclusive scan of bucket histograms (k_scan2 replacement) ----
    sA[tid] = pcur[tid];
    sB[tid] = pcnt_m[tid];
    __syncthreads();
    for (int off = 1; off < 256; off <<= 1) {
        int uA = (tid >= off) ? sA[tid - off] : 0;
        int uB = (tid >= off) ? sB[tid - off] : 0;
        __syncthreads();
        sA[tid] += uA; sB[tid] += uB;
        __syncthreads();
    }
    int lo      = (b > 0) ? sA[b - 1] : 0;
    int lom     = (b > 0) ? sB[b - 1] : 0;
    int cnt_tot = sA[b] - lo;

    const int* eb = ebuf + (size_t)b * BCAP;
    int dbase = b << shift;
    for (int j = tid; j < 512; j += 256) { cnt[j] = 0; cnt_m[j] = 0; }
    __syncthreads();
    for (int i = tid; i < cnt_tot; i += 256) {
        int pk = eb[i];
        int dlo = (pk >> 20) & 511;
        atomicAdd(&cnt[dlo], 1);
        if (pk >> 29) atomicAdd(&cnt_m[dlo], 1);
    }
    __syncthreads();
    int c0 = cnt[2 * tid], c1 = cnt[2 * tid + 1];
    int ps = c0 + c1;
    tmp[tid] = ps;
    __syncthreads();
    for (int off = 1; off < 256; off <<= 1) {
        int u = (tid >= off) ? tmp[tid - off] : 0;
        __syncthreads();
        tmp[tid] += u;
        __syncthreads();
    }
    int pre = tmp[tid] - ps;
    cur[2 * tid] = pre;
    cur[2 * tid + 1] = pre + c0;
    __syncthreads();
    int m0 = cnt_m[2 * tid], m1 = cnt_m[2 * tid + 1];
    int psm = m0 + m1;
    tmp[tid] = psm;
    __syncthreads();
    for (int off = 1; off < 256; off <<= 1) {
        int u = (tid >= off) ? tmp[tid - off] : 0;
        __syncthreads();
        tmp[tid] += u;
        __syncthreads();
    }
    int prem = tmp[tid] - psm;
    cur_m[2 * tid] = prem;
    cur_m[2 * tid + 1] = prem + m0;
    __syncthreads();
    int nd = n - dbase; if (nd > 512) nd = 512;
    for (int j = tid; j < nd; j += 256) {
        indptr[dbase + j] = lo + cur[j];
        indptr_m[dbase + j] = lom + cur_m[j];
        dinv[dbase + j] = rsqrtf((float)cnt[j] + 1.0f);   // self-loop adds 1
    }
    if (b == 0 && tid == 0) {
        indptr[n] = sA[255];
        indptr_m[n] = sB[255];
    }
    __syncthreads();
    for (int i = tid; i < cnt_tot; i += 256) {
        int pk = eb[i];
        int s = pk & 0xFFFFF;
        int dlo = (pk >> 20) & 511;
        int pos = lo + atomicAdd(&cur[dlo], 1);
        out_all[pos] = s;
        if (pk >> 29) {
            int pm = lom + atomicAdd(&cur_m[dlo], 1);
            out_m[pm] = s;
        }
    }
}

// ---------------- prep: weight transposes + x prescale in ONE dispatch ----
// blocks [0,640): wprep body; blocks [640, 2688): cvt_pre grid-stride body.
__global__ __launch_bounds__(256) void k_prep(
    const float* __restrict__ Wo, const float* __restrict__ Wti,
    const float* __restrict__ Wenc,
    const float* __restrict__ p1W1, const float* __restrict__ p1W2,
    const float* __restrict__ p0W1, const float* __restrict__ p0W2,
    const float* __restrict__ dW1, const float* __restrict__ dW2,
    unsigned short* __restrict__ Wcat_t, unsigned short* __restrict__ Wenc_t,
    unsigned short* __restrict__ o1, unsigned short* __restrict__ o2,
    unsigned short* __restrict__ o3, unsigned short* __restrict__ o4,
    unsigned short* __restrict__ o5, unsigned short* __restrict__ o6,
    const float* __restrict__ x, const float* __restrict__ dinv,
    unsigned short* __restrict__ xp, int total4) {
    int bid = blockIdx.x;
    if (bid < 640) {
        int idx = bid * 256 + threadIdx.x;
        if (idx < 32768) {
            int j = idx >> 7, k = idx & 127;
            float v = (j < 128) ? Wo[(k << 7) + j] : Wti[(k << 7) + j - 128];
            Wcat_t[idx] = f2bf(v);
        } else if (idx < 65536) {
            int i = idx - 32768;
            Wenc_t[(size_t)(i & 127) * 256 + (i >> 7)] = f2bf(Wenc[i]);
        } else {
            int i2 = idx - 65536;
            int h = i2 >> 14;
            int i = i2 & 16383;
            const float* W; unsigned short* O;
            switch (h) {
                case 0: W = p1W1; O = o1; break;
                case 1: W = p1W2; O = o2; break;
                case 2: W = p0W1; O = o3; break;
                case 3: W = p0W2; O = o4; break;
                case 4: W = dW1;  O = o5; break;
                default: W = dW2; O = o6; break;
            }
            O[(i & 127) * 128 + (i >> 7)] = f2bf(W[i]);
        }
    } else {
        int i = (bid - 640) * 256 + threadIdx.x;
        const int stride = 2048 * 256;
        for (; i < total4; i += stride) {
            float dv = dinv[i >> 5];
            float4 v = ((const float4*)x)[i];
            ushort4 o;
            o.x = f2bf(v.x * dv); o.y = f2bf(v.y * dv);
            o.z = f2bf(v.z * dv); o.w = f2bf(v.w * dv);
            ((ushort4*)xp)[i] = o;
        }
    }
}

// ---------------- graph: aggregate x_pre ----------------
__global__ __launch_bounds__(256) void k_aggx(const unsigned short* __restrict__ xp,
                                              const int* __restrict__ indptr,
                                              const int* __restrict__ srcs,
                                              const float* __restrict__ dinv,
                                              unsigned short* __restrict__ aggx, int n) {
    int wv = threadIdx.x >> 6, lane = threadIdx.x & 63;
    int v = blockIdx.x * 4 + wv;
    if (v >= n) return;
    const unsigned* xp2 = (const unsigned*)xp;
    int beg = indptr[v], end = indptr[v + 1];
    unsigned sv = xp2[(size_t)v * 64 + lane];
    float a0 = bflo(sv), a1 = bfhi(sv);
    int i = beg;
    for (; i + 8 <= end; i += 8) {
        int s0 = srcs[i], s1 = srcs[i + 1], s2 = srcs[i + 2], s3 = srcs[i + 3];
        int s4 = srcs[i + 4], s5 = srcs[i + 5], s6 = srcs[i + 6], s7 = srcs[i + 7];
        unsigned u0 = xp2[(size_t)s0 * 64 + lane];
        unsigned u1 = xp2[(size_t)s1 * 64 + lane];
        unsigned u2 = xp2[(size_t)s2 * 64 + lane];
        unsigned u3 = xp2[(size_t)s3 * 64 + lane];
        unsigned u4 = xp2[(size_t)s4 * 64 + lane];
        unsigned u5 = xp2[(size_t)s5 * 64 + lane];
        unsigned u6 = xp2[(size_t)s6 * 64 + lane];
        unsigned u7 = xp2[(size_t)s7 * 64 + lane];
        a0 += bflo(u0) + bflo(u1) + bflo(u2) + bflo(u3)
            + bflo(u4) + bflo(u5) + bflo(u6) + bflo(u7);
        a1 += bfhi(u0) + bfhi(u1) + bfhi(u2) + bfhi(u3)
            + bfhi(u4) + bfhi(u5) + bfhi(u6) + bfhi(u7);
    }
    for (; i + 4 <= end; i += 4) {
        int s0 = srcs[i], s1 = srcs[i + 1], s2 = srcs[i + 2], s3 = srcs[i + 3];
        unsigned u0 = xp2[(size_t)s0 * 64 + lane];
        unsigned u1 = xp2[(size_t)s1 * 64 + lane];
        unsigned u2 = xp2[(size_t)s2 * 64 + lane];
        unsigned u3 = xp2[(size_t)s3 * 64 + lane];
        a0 += bflo(u0) + bflo(u1) + bflo(u2) + bflo(u3);
        a1 += bfhi(u0) + bfhi(u1) + bfhi(u2) + bfhi(u3);
    }
    for (; i < end; ++i) {
        unsigned u = xp2[(size_t)srcs[i] * 64 + lane];
        a0 += bflo(u); a1 += bfhi(u);
    }
    float dv = dinv[v];
    a0 *= dv; a1 *= dv;
    unsigned o = (unsigned)f2bf(a0) | ((unsigned)f2bf(a1) << 16);
    ((unsigned*)aggx)[(size_t)v * 64 + lane] = o;
}

// ---------------- GCN gemm: [r_o|r_t] = relu(aggx @ Wcat + [b_o|b_t]), e fused
__global__ __launch_bounds__(256) void k_gcn(const unsigned short* __restrict__ aggx,
                                             const unsigned short* __restrict__ Wcat,
                                             const float* __restrict__ b_o,
                                             const float* __restrict__ b_t,
                                             const float* __restrict__ a_w,
                                             const float* __restrict__ a_b,
                                             unsigned short* __restrict__ cat2,
                                             unsigned short* __restrict__ rt,
                                             float* __restrict__ e, int M) {
    __shared__ short ct[64][264];   // 64 rows x 256 cols bf16 (+8 pad, 528B rows)
    int wave = threadIdx.x >> 6, lane = threadIdx.x & 63;
    int row_base = blockIdx.x * 64 + wave * 16;
    int rA = row_base + (lane & 15);
    if (rA >= M) rA = M - 1;
    int koff = (lane >> 4) << 3;
    int colL = lane & 15;

    bf16x8 a[4];
#pragma unroll
    for (int ks = 0; ks < 4; ++ks)
        a[ks] = *(const bf16x8*)((const short*)aggx + (size_t)rA * 128 + (ks << 5) + koff);

    f32x4 acc[16];
#pragma unroll
    for (int cf = 0; cf < 16; ++cf) acc[cf] = (f32x4){0.f, 0.f, 0.f, 0.f};
#pragma unroll
    for (int ks = 0; ks < 4; ++ks)
#pragma unroll
        for (int cf = 0; cf < 16; ++cf) {
            bf16x8 b = *(const bf16x8*)((const short*)Wcat + (size_t)((cf << 4) + colL) * 128 + (ks << 5) + koff);
            acc[cf] = __builtin_amdgcn_mfma_f32_16x16x32_bf16(a[ks], b, acc[cf], 0, 0, 0);
        }

    float ep0 = 0.f, ep1 = 0.f, ep2 = 0.f, ep3 = 0.f;
    int rl0 = wave * 16 + ((lane >> 4) << 2);
#pragma unroll
    for (int cf = 0; cf < 16; ++cf) {
        int col = (cf << 4) + colL;
        float bv = (col < 128) ? b_o[col] : b_t[col - 128];
        float aw = a_w[col];
#pragma unroll
        for (int j = 0; j < 4; ++j) {
            float v = fmaxf(acc[cf][j] + bv, 0.f);
            if (j == 0) ep0 += v * aw;
            else if (j == 1) ep1 += v * aw;
            else if (j == 2) ep2 += v * aw;
            else ep3 += v * aw;
            ct[rl0 + j][col] = (short)f2bf(v);
        }
    }
#pragma unroll
    for (int mk = 1; mk < 16; mk <<= 1) {
        ep0 += __shfl_xor(ep0, mk); ep1 += __shfl_xor(ep1, mk);
        ep2 += __shfl_xor(ep2, mk); ep3 += __shfl_xor(ep3, mk);
    }
    if (colL == 0) {
        float ab = a_b[0];
        int r0 = row_base + ((lane >> 4) << 2);
        if (r0 + 0 < M) e[r0 + 0] = ep0 + ab;
        if (r0 + 1 < M) e[r0 + 1] = ep1 + ab;
        if (r0 + 2 < M) e[r0 + 2] = ep2 + ab;
        if (r0 + 3 < M) e[r0 + 3] = ep3 + ab;
    }
    __syncthreads();
    int base64 = blockIdx.x * 64;
    short* cp = (short*)cat2 + (size_t)base64 * 256;
    for (int j = threadIdx.x; j < 1024; j += 256) {
        int row = j >> 4;
        if (base64 + row < M)
            *(s16x8*)(cp + (size_t)row * 256 + ((j & 15) << 3)) =
                *(const s16x8*)&ct[row][(j & 15) << 3];
    }
    short* rp = (short*)rt + (size_t)base64 * 128;
    for (int j = threadIdx.x; j < 1024; j += 256) {
        int row = j >> 4;
        if (base64 + row < M)
            *(s16x8*)(rp + (size_t)row * 128 + ((j & 15) << 3)) =
                *(const s16x8*)&ct[row][128 + ((j & 15) << 3)];
    }
}

// ---------------- masked attention (masked CSR only) ----------------
__global__ __launch_bounds__(256) void k_attn(const unsigned short* __restrict__ rt,
                                              const int* __restrict__ indptr_m,
                                              const int* __restrict__ srcs_m,
                                              const float* __restrict__ e,
                                              unsigned short* __restrict__ cat2, int n) {
    int wv = threadIdx.x >> 6, lane = threadIdx.x & 63;
    int v = blockIdx.x * 4 + wv;
    if (v >= n) return;
    float ev = e[v];
    int bm = indptr_m[v], em = indptr_m[v + 1];
    float m = -INFINITY;
    for (int i = bm + lane; i < em; i += 64)
        m = fmaxf(m, lrelu02(ev + e[srcs_m[i]]));
    for (int off = 32; off; off >>= 1) m = fmaxf(m, __shfl_xor(m, off));
    if (bm == em) m = 0.f;
    float h0 = 0.f, h1 = 0.f, wsum = 0.f;
    const unsigned* rt2 = (const unsigned*)rt;
    int i = bm;
    for (; i + 8 <= em; i += 8) {
        int s0 = srcs_m[i], s1 = srcs_m[i + 1], s2 = srcs_m[i + 2], s3 = srcs_m[i + 3];
        int s4 = srcs_m[i + 4], s5 = srcs_m[i + 5], s6 = srcs_m[i + 6], s7 = srcs_m[i + 7];
        float w0 = __expf(lrelu02(ev + e[s0]) - m);
        float w1 = __expf(lrelu02(ev + e[s1]) - m);
        float w2 = __expf(lrelu02(ev + e[s2]) - m);
        float w3 = __expf(lrelu02(ev + e[s3]) - m);
        float w4 = __expf(lrelu02(ev + e[s4]) - m);
        float w5 = __expf(lrelu02(ev + e[s5]) - m);
        float w6 = __expf(lrelu02(ev + e[s6]) - m);
        float w7 = __expf(lrelu02(ev + e[s7]) - m);
        unsigned u0 = rt2[(size_t)s0 * 64 + lane];
        unsigned u1 = rt2[(size_t)s1 * 64 + lane];
        unsigned u2 = rt2[(size_t)s2 * 64 + lane];
        unsigned u3 = rt2[(size_t)s3 * 64 + lane];
        unsigned u4 = rt2[(size_t)s4 * 64 + lane];
        unsigned u5 = rt2[(size_t)s5 * 64 + lane];
        unsigned u6 = rt2[(size_t)s6 * 64 + lane];
        unsigned u7 = rt2[(size_t)s7 * 64 + lane];
        wsum += w0 + w1 + w2 + w3 + w4 + w5 + w6 + w7;
        h0 += w0 * bflo(u0) + w1 * bflo(u1) + w2 * bflo(u2) + w3 * bflo(u3)
            + w4 * bflo(u4) + w5 * bflo(u5) + w6 * bflo(u6) + w7 * bflo(u7);
        h1 += w0 * bfhi(u0) + w1 * bfhi(u1) + w2 * bfhi(u2) + w3 * bfhi(u3)
            + w4 * bfhi(u4) + w5 * bfhi(u5) + w6 * bfhi(u6) + w7 * bfhi(u7);
    }
    for (; i < em; ++i) {
        int s = srcs_m[i];
        float w = __expf(lrelu02(ev + e[s]) - m);
        unsigned u = rt2[(size_t)s * 64 + lane];
        wsum += w;
        h0 += w * bflo(u);
        h1 += w * bfhi(u);
    }
    float inv = 1.f / (wsum + 1e-16f);
    unsigned o = (unsigned)f2bf(h0 * inv) | ((unsigned)f2bf(h1 * inv) << 16);
    ((unsigned*)(cat2 + (size_t)v * 256 + 128))[lane] = o;
}

// ---------------- fused tail: z_enc GEMM + 3 MLP heads + select/sigmoid ----
// 512 threads / 8 waves / 128 rows per block; wave owns 16 rows. Pool 69632 B
// (2 blocks/CU, 16 waves/CU): Wa [128][136] shorts (34816 B) overlaid by zt
// [64][132] fp32 (33792 B); hb [128][136] shorts (34816 B, wave-indexed).
// Phase-1 zt staging in 2 chunks (waves 0-3, then 4-7).
__global__ __launch_bounds__(512) void k_tail(
    const unsigned short* __restrict__ cat2, const unsigned short* __restrict__ rt_bf,
    const unsigned short* __restrict__ Wenc, const float* __restrict__ b_enc,
    const unsigned short* __restrict__ W11, const float* __restrict__ b11,
    const unsigned short* __restrict__ W12, const float* __restrict__ b12,
    const float* __restrict__ W13, const float* __restrict__ b13,
    const unsigned short* __restrict__ W01, const float* __restrict__ b01,
    const unsigned short* __restrict__ W02, const float* __restrict__ b02,
    const float* __restrict__ W03, const float* __restrict__ b03,
    const unsigned short* __restrict__ Wd1, const float* __restrict__ bd1,
    const unsigned short* __restrict__ Wd2, const float* __restrict__ bd2,
    const float* __restrict__ Wd3, const float* __restrict__ bd3,
    const int* __restrict__ t, float* __restrict__ zenc,
    float* __restrict__ out, int M) {
    __shared__ __align__(16) char pool[128 * 136 * 2 + 128 * 136 * 2];   // 69632 B
    short* Wa = (short*)pool;                       // 34816 B
    short* hb = (short*)(pool + 128 * 136 * 2);     // 34816 B
    float* zt = (float*)pool;                       // [64][132] fp32 = 33792 B

    int wave = threadIdx.x >> 6, lane = threadIdx.x & 63;
    int colL = lane & 15;
    int koff = (lane >> 4) << 3;
    int base128 = blockIdx.x * 128;
    int rA = base128 + wave * 16 + colL;
    if (rA >= M) rA = M - 1;

    // ra frags (discriminator input) — load early, hides under phase 1
    bf16x8 ra[4];
#pragma unroll
    for (int ks = 0; ks < 4; ++ks)
        ra[ks] = *(const bf16x8*)((const short*)rt_bf + (size_t)rA * 128 + (ks << 5) + koff);

    // ---- phase 1: z_enc (K=256, Ncols=128) for this wave's 16 rows ----
    f32x4 acc1[8];
    {
        const short* Ap = (const short*)cat2 + (size_t)rA * 256 + koff;
        const short* Bp = (const short*)Wenc + (size_t)colL * 256 + koff;
#pragma unroll
        for (int cf = 0; cf < 8; ++cf) acc1[cf] = (f32x4){0.f, 0.f, 0.f, 0.f};
#pragma unroll
        for (int ks = 0; ks < 8; ++ks) {
            bf16x8 a = *(const bf16x8*)(Ap + (ks << 5));
#pragma unroll
            for (int cf = 0; cf < 8; ++cf) {
                bf16x8 b = *(const bf16x8*)(Bp + (size_t)(cf << 4) * 256 + (ks << 5));
                acc1[cf] = __builtin_amdgcn_mfma_f32_16x16x32_bf16(a, b, acc1[cf], 0, 0, 0);
            }
        }
    }

    // ---- zt staging + zenc writeout + za extraction, in 2 wave-group chunks
    bf16x8 za[4];
#pragma unroll
    for (int chunk = 0; chunk < 2; ++chunk) {
        if ((wave >> 2) == chunk) {
            int rl0 = (wave & 3) * 16 + ((lane >> 4) << 2);
#pragma unroll
            for (int cf = 0; cf < 8; ++cf) {
                int col = (cf << 4) + colL;
                float bv = b_enc[col];
#pragma unroll
                for (int j = 0; j < 4; ++j)
                    zt[(rl0 + j) * 132 + col] = acc1[cf][j] + bv;
            }
        }
        __syncthreads();
        {   // cooperative linear fp32 writeout of this chunk's 64x128 region
            int gbase = base128 + chunk * 64;
            float* zp = zenc + (size_t)gbase * 128;
            for (int j = threadIdx.x; j < 2048; j += 512) {
                int row = j >> 5;
                if (gbase + row < M)
                    *(float4*)(zp + (size_t)j * 4) = *(const float4*)&zt[row * 132 + ((j & 31) << 2)];
            }
        }
        if ((wave >> 2) == chunk) {
            int rAl = (wave & 3) * 16 + colL;
#pragma unroll
            for (int ks = 0; ks < 4; ++ks) {
                float4 v0 = *(const float4*)&zt[rAl * 132 + (ks << 5) + koff];
                float4 v1 = *(const float4*)&zt[rAl * 132 + (ks << 5) + koff + 4];
                za[ks][0] = (short)f2bf(v0.x); za[ks][1] = (short)f2bf(v0.y);
                za[ks][2] = (short)f2bf(v0.z); za[ks][3] = (short)f2bf(v0.w);
                za[ks][4] = (short)f2bf(v1.x); za[ks][5] = (short)f2bf(v1.y);
                za[ks][6] = (short)f2bf(v1.z); za[ks][7] = (short)f2bf(v1.w);
            }
        }
        __syncthreads();   // zt reads done before next chunk / Wa staging
    }

    float sp1[4], sp0[4], sdd[4];

    auto stage = [&](const unsigned short* W) {
        for (int i = threadIdx.x; i < 2048; i += 512) {
            int r = i >> 4, c = (i & 15) << 3;
            bf16x8 v = *(const bf16x8*)((const short*)W + (r << 7) + c);
            *(bf16x8*)(Wa + r * 136 + c) = v;
        }
    };

    auto run_head = [&](const bf16x8* A0,
                        const unsigned short* W1, const float* b1,
                        const unsigned short* W2, const float* b2,
                        const float* W3, const float* b3, float* sout) {
        __syncthreads();   // Wa/hb reads of previous head done (1st call: zt done)
        stage(W1);
        __syncthreads();
        f32x4 acc[8];
#pragma unroll
        for (int cf = 0; cf < 8; ++cf) acc[cf] = (f32x4){0.f, 0.f, 0.f, 0.f};
#pragma unroll
        for (int ks = 0; ks < 4; ++ks)
#pragma unroll
            for (int cf = 0; cf < 8; ++cf) {
                bf16x8 b = *(const bf16x8*)(Wa + ((cf << 4) + colL) * 136 + (ks << 5) + koff);
                acc[cf] = __builtin_amdgcn_mfma_f32_16x16x32_bf16(A0[ks], b, acc[cf], 0, 0, 0);
            }
        short* hw = hb + wave * 2176;   // 16 rows x 136 shorts per wave
#pragma unroll
        for (int cf = 0; cf < 8; ++cf) {
            int col = (cf << 4) + colL;
            float bv = b1[col];
#pragma unroll
            for (int j = 0; j < 4; ++j)
                hw[(((lane >> 4) << 2) + j) * 136 + col] = (short)f2bf(lrelu02(acc[cf][j] + bv));
        }
        __syncthreads();   // all MFMA1 reads of Wa done; hb written
        stage(W2);
        __syncthreads();
        bf16x8 h1f[4];
#pragma unroll
        for (int ks = 0; ks < 4; ++ks)
            h1f[ks] = *(const bf16x8*)(hw + colL * 136 + (ks << 5) + koff);
#pragma unroll
        for (int cf = 0; cf < 8; ++cf) acc[cf] = (f32x4){0.f, 0.f, 0.f, 0.f};
#pragma unroll
        for (int ks = 0; ks < 4; ++ks)
#pragma unroll
            for (int cf = 0; cf < 8; ++cf) {
                bf16x8 b = *(const bf16x8*)(Wa + ((cf << 4) + colL) * 136 + (ks << 5) + koff);
                acc[cf] = __builtin_amdgcn_mfma_f32_16x16x32_bf16(h1f[ks], b, acc[cf], 0, 0, 0);
            }
        float s0 = 0.f, s1 = 0.f, s2 = 0.f, s3 = 0.f;
#pragma unroll
        for (int cf = 0; cf < 8; ++cf) {
            int col = (cf << 4) + colL;
            float w3 = W3[col], bv = b2[col];
            s0 += lrelu02(acc[cf][0] + bv) * w3;
            s1 += lrelu02(acc[cf][1] + bv) * w3;
            s2 += lrelu02(acc[cf][2] + bv) * w3;
            s3 += lrelu02(acc[cf][3] + bv) * w3;
        }
#pragma unroll
        for (int mk = 1; mk < 16; mk <<= 1) {
            s0 += __shfl_xor(s0, mk); s1 += __shfl_xor(s1, mk);
            s2 += __shfl_xor(s2, mk); s3 += __shfl_xor(s3, mk);
        }
        float bb = b3[0];
        sout[0] = s0 + bb; sout[1] = s1 + bb; sout[2] = s2 + bb; sout[3] = s3 + bb;
    };

    run_head(za, W11, b11, W12, b12, W13, b13, sp1);
    run_head(za, W01, b01, W02, b02, W03, b03, sp0);
    run_head(ra, Wd1, bd1, Wd2, bd2, Wd3, bd3, sdd);

    if (colL == 0) {
#pragma unroll
        for (int j = 0; j < 4; ++j) {
            int row = base128 + wave * 16 + ((lane >> 4) << 2) + j;
            if (row < M) {
                out[row] = 1.f / (1.f + __expf(-sdd[j]));           // pred_t
                out[M + row] = (t[row] > 0) ? sp1[j] : sp0[j];      // pred
            }
        }
    }
}

// ---------------- launcher ----------------

extern "C" void kernel_launch(void* const* d_in, const int* in_sizes, int n_in,
                              void* d_out, int out_size, void* d_ws, size_t ws_size,
                              hipStream_t stream) {
    const float* x     = (const float*)d_in[0];
    const int*   t     = (const int*)d_in[1];
    const int*   ei    = (const int*)d_in[3];
    const float* W_o   = (const float*)d_in[4];
    const float* b_o   = (const float*)d_in[5];
    const float* W_t   = (const float*)d_in[6];
    const float* b_t   = (const float*)d_in[7];
    const float* a_w   = (const float*)d_in[8];
    const float* a_b   = (const float*)d_in[9];
    const float* W_enc = (const float*)d_in[10];
    const float* b_enc = (const float*)d_in[11];
    const float* p1_W1 = (const float*)d_in[12]; const float* p1_b1 = (const float*)d_in[13];
    const float* p1_W2 = (const float*)d_in[14]; const float* p1_b2 = (const float*)d_in[15];
    const float* p1_W3 = (const float*)d_in[16]; const float* p1_b3 = (const float*)d_in[17];
    const float* p0_W1 = (const float*)d_in[18]; const float* p0_b1 = (const float*)d_in[19];
    const float* p0_W2 = (const float*)d_in[20]; const float* p0_b2 = (const float*)d_in[21];
    const float* p0_W3 = (const float*)d_in[22]; const float* p0_b3 = (const float*)d_in[23];
    const float* d_W1  = (const float*)d_in[24]; const float* d_b1  = (const float*)d_in[25];
    const float* d_W2  = (const float*)d_in[26]; const float* d_b2  = (const float*)d_in[27];
    const float* d_W3  = (const float*)d_in[28]; const float* d_b3  = (const float*)d_in[29];

    const int n = in_sizes[1];
    const int E = in_sizes[3] / 2;
    const int* src = ei;
    const int* dst = ei + E;

    float* out  = (float*)d_out;
    float* zenc = out + 2 * (size_t)n;   // output: pred_t[N], pred[N], z_enc[N,128]

    const int shift = 9;
    const int NB = (n + (1 << shift) - 1) >> shift;

    // ---- workspace layout ----
    char* base = (char*)d_ws;
    size_t o = 0;
    auto alloc = [&](size_t bytes) { char* p = base + o; o += (bytes + 255) & ~(size_t)255; return p; };
    unsigned short* xp_bf   = (unsigned short*)alloc((size_t)n * 128 * 2);
    unsigned short* aggx_bf = (unsigned short*)alloc((size_t)n * 128 * 2);
    unsigned short* cat2_bf = (unsigned short*)alloc((size_t)n * 256 * 2);
    unsigned short* rt_bf   = (unsigned short*)alloc((size_t)n * 128 * 2);
    float* dinv = (float*)alloc((size_t)n * 4);
    float* evec = (float*)alloc((size_t)n * 4);
    unsigned short* Wcat_t = (unsigned short*)alloc(256 * 128 * 2);
    unsigned short* Wenc_t = (unsigned short*)alloc(128 * 256 * 2);
    unsigned short* Wp1a_t = (unsigned short*)alloc(128 * 128 * 2);
    unsigned short* Wp1b_t = (unsigned short*)alloc(128 * 128 * 2);
    unsigned short* Wp0a_t = (unsigned short*)alloc(128 * 128 * 2);
    unsigned short* Wp0b_t = (unsigned short*)alloc(128 * 128 * 2);
    unsigned short* Wda_t  = (unsigned short*)alloc(128 * 128 * 2);
    unsigned short* Wdb_t  = (unsigned short*)alloc(128 * 128 * 2);
    int* indptr     = (int*)alloc(((size_t)n + 1) * 4);
    int* indptr_m   = (int*)alloc(((size_t)n + 1) * 4);
    int* pcur       = (int*)alloc(514 * 4);          // pcur[257] + pcnt_m[257]
    int* pcnt_m     = pcur + 257;
    int* src_sorted = (int*)alloc((size_t)E * 4);
    int* src_mask   = (int*)alloc((size_t)E * 4);
    int* ebuf       = (int*)alloc((size_t)256 * BCAP * 4);   // padded buckets

    const int mt  = (n + 63) / 64;
    const int mt2 = (n + 127) / 128;

    // ---- CSR build (single edge pass; scan folded into sortC) ----
    hipMemsetAsync(pcur, 0, 514 * 4, stream);
    k_fillB<<<(E + 4095) / 4096, 256, 0, stream>>>(src, dst, t, pcur, pcnt_m, ebuf, E, shift);
    k_sortC<<<NB, 256, 0, stream>>>(ebuf, pcur, pcnt_m, indptr, indptr_m, dinv,
                                    src_sorted, src_mask, n, shift, NB);

    // ---- prep: weight transposes + x prescale (single dispatch) ----
    k_prep<<<2688, 256, 0, stream>>>(W_o, W_t, W_enc, p1_W1, p1_W2, p0_W1, p0_W2,
                                     d_W1, d_W2, Wcat_t, Wenc_t,
                                     Wp1a_t, Wp1b_t, Wp0a_t, Wp0b_t, Wda_t, Wdb_t,
                                     x, dinv, xp_bf, n * 32);

    // aggregate prescaled x over full CSR
    k_aggx<<<(n + 3) / 4, 256, 0, stream>>>(xp_bf, indptr, src_sorted, dinv, aggx_bf, n);

    // [r_o|r_t] = relu(aggx @ Wcat + bias); e fused
    k_gcn<<<mt, 256, 0, stream>>>(aggx_bf, Wcat_t, b_o, b_t, a_w, a_b,
                                  cat2_bf, rt_bf, evec, n);

    // attention -> h (masked CSR only)
    k_attn<<<(n + 3) / 4, 256, 0, stream>>>(rt_bf, indptr_m, src_mask, evec, cat2_bf, n);

    // fused: z_enc + 3 heads + select/sigmoid (512 threads, 128 rows/block)
    k_tail<<<mt2, 512, 0, stream>>>(cat2_bf, rt_bf, Wenc_t, b_enc,
                                    Wp1a_t, p1_b1, Wp1b_t, p1_b2, p1_W3, p1_b3,
                                    Wp0a_t, p0_b1, Wp0b_t, p0_b2, p0_W3, p0_b3,
                                    Wda_t, d_b1, Wdb_t, d_b2, d_W3, d_b3,
                                    t, zenc, out, n);
}